// Round 25
// baseline (99.002 us; speedup 1.0000x reference)
//
#include <hip/hip_runtime.h>
#include <math.h>

// Problem dims
#define BSZ   256
#define LDIM  128
#define PDIM  3
#define HDIM  512
#define DDIM  32
#define NDIM  50
#define NEDGE 1225   // N*(N-1)/2
#define EOUT  5      // EDIM+1
#define NRH   4      // r-splits: 4 x 128 cols
#define ECH   128    // cols per edge block

// ws layout (floats):
//   u @0 (131072), pW1 @131072 (25600), n1 @156672 (131072),
//   P_h @287744 (3136000 fl), nl_h @6559744 (204800),
//   W1p @6764544 (131072), Wep @6895616 (131072), Wsp @7026688 (65536),
//   Winp @7092224 (34816), Wn2p @7127040 (409600), Weeh @7536640 (16384)

typedef _Float16 v2h __attribute__((ext_vector_type(2)));

__device__ __forceinline__ float fdot2f(v2h a, v2h b, float c) {
    return __builtin_amdgcn_fdot2(a, b, c, false);
}
__device__ __forceinline__ v2h relu2(v2h a, v2h b) {
    v2h s = a + b;
    v2h z = {(_Float16)0.f, (_Float16)0.f};
    return __builtin_elementwise_max(s, z);
}
struct h4 { v2h lo, hi; };
struct h8 { v2h a, b, c, d; };   // 16B

// ============ k_prep: pack weights into fp16 k-pair layouts ================
__global__ __launch_bounds__(256) void k_prep(
        const float* __restrict__ W_n1, const float* __restrict__ W_e1,
        const float* __restrict__ W_s1, const float* __restrict__ W_in,
        const float* __restrict__ W_n2,
        v2h* __restrict__ W1p, v2h* __restrict__ Wep,
        v2h* __restrict__ Wsp, v2h* __restrict__ Winp,
        v2h* __restrict__ Wn2p, v2h* __restrict__ Weeh) {
    int f = blockIdx.x * 256 + threadIdx.x;
    if (f < 131072) {
        int q = f & 3, t1 = f >> 2, j = t1 & 511, k8 = t1 >> 9;
        int k2 = k8 * 4 + q;
        v2h w;
        w.x = (_Float16)W_n1[(size_t)(2 * k2) * HDIM + j];
        w.y = (_Float16)W_n1[(size_t)(2 * k2 + 1) * HDIM + j];
        W1p[f] = w;
    } else if (f < 262144) {
        int g = f - 131072;
        int q = g & 3, t1 = g >> 2, j = t1 & 511, k8 = t1 >> 9;
        int k2 = k8 * 4 + q;
        v2h w;
        w.x = (_Float16)W_e1[(size_t)(2 * k2) * HDIM + j];
        w.y = (_Float16)W_e1[(size_t)(2 * k2 + 1) * HDIM + j];
        Wep[g] = w;
    } else if (f < 327680) {
        int g = f - 262144;
        int q = g & 3, t1 = g >> 2, j = t1 & 255, k8 = t1 >> 8;
        int k2 = k8 * 4 + q;
        v2h w;
        w.x = (_Float16)W_s1[(size_t)(2 * k2) * (HDIM / 2) + j];
        w.y = (_Float16)W_s1[(size_t)(2 * k2 + 1) * (HDIM / 2) + j];
        Wsp[g] = w;
    } else if (f < 362496) {
        int g = f - 327680;
        int q = g & 3, t1 = g >> 2, j = t1 & 511, k8 = t1 >> 9;
        int k2 = k8 * 4 + q;     // 0..67
        int r0 = 2 * k2, r1 = 2 * k2 + 1;
        v2h w;
        w.x = (r0 < LDIM + PDIM) ? (_Float16)W_in[(size_t)r0 * HDIM + j] : (_Float16)0.f;
        w.y = (r1 < LDIM + PDIM) ? (_Float16)W_in[(size_t)r1 * HDIM + j] : (_Float16)0.f;
        Winp[g] = w;
    } else if (f < 772096) {
        int g = f - 362496;
        int q = g & 3, t1 = g >> 2;      // t1 < 102400
        int j = t1 % 1600, k8 = t1 / 1600;   // k8 < 64
        int k2 = k8 * 4 + q;             // < 256
        v2h w;
        w.x = (_Float16)W_n2[(size_t)(2 * k2) * 1600 + j];
        w.y = (_Float16)W_n2[(size_t)(2 * k2 + 1) * 1600 + j];
        Wn2p[g] = w;
    } else if (f < 772096 + 16384) {
        int g = f - 772096;              // [arr][col][k2]
        int k2 = g & 15, col = (g >> 4) & 511, arr = g >> 13;
        v2h w;
        w.x = (_Float16)W_e1[(size_t)(HDIM + arr * DDIM + 2 * k2) * HDIM + col];
        w.y = (_Float16)W_e1[(size_t)(HDIM + arr * DDIM + 2 * k2 + 1) * HDIM + col];
        Weeh[g] = w;
    }
}

// helper: stage packed inputs [2][68] v2h from z/tp
__device__ __forceinline__ void stage_sin2(v2h* sin2, const float* z, const float* tp,
                                           int b0, int t) {
    if (t < 136) {
        int bi = (t >= 68) ? 1 : 0;
        int k2 = t - (bi ? 68 : 0);
        int k0 = 2 * k2, k1 = 2 * k2 + 1;
        float v0 = (k0 < LDIM) ? z[(size_t)(b0 + bi) * LDIM + k0]
                 : (k0 < LDIM + PDIM) ? tp[(size_t)(b0 + bi) * PDIM + (k0 - LDIM)] : 0.f;
        float v1 = (k1 < LDIM) ? z[(size_t)(b0 + bi) * LDIM + k1]
                 : (k1 < LDIM + PDIM) ? tp[(size_t)(b0 + bi) * PDIM + (k1 - LDIM)] : 0.f;
        v2h v; v.x = (_Float16)v0; v.y = (_Float16)v1;
        sin2[bi * 68 + k2] = v;
    }
}

// helper: phase1 h for 2 batches via packed W_in; writes sh[2][512] fp32
__device__ __forceinline__ void phase1_h(const v2h* sin2, const v2h* Winp,
                                         const float* b_in, float* sh, int t) {
    float bin0 = b_in[t], bin1 = b_in[t + 256];
    float a00 = bin0, a01 = bin1, a10 = bin0, a11 = bin1;
    for (int k8 = 0; k8 < 17; ++k8) {
        h8 s0 = *reinterpret_cast<const h8*>(&sin2[k8 * 4]);
        h8 s1 = *reinterpret_cast<const h8*>(&sin2[68 + k8 * 4]);
        h8 w0 = *reinterpret_cast<const h8*>(&Winp[(size_t)(k8 * 512 + t) * 4]);
        h8 w1 = *reinterpret_cast<const h8*>(&Winp[(size_t)(k8 * 512 + t + 256) * 4]);
        a00 = fdot2f(s0.a, w0.a, a00); a00 = fdot2f(s0.b, w0.b, a00);
        a00 = fdot2f(s0.c, w0.c, a00); a00 = fdot2f(s0.d, w0.d, a00);
        a01 = fdot2f(s0.a, w1.a, a01); a01 = fdot2f(s0.b, w1.b, a01);
        a01 = fdot2f(s0.c, w1.c, a01); a01 = fdot2f(s0.d, w1.d, a01);
        a10 = fdot2f(s1.a, w0.a, a10); a10 = fdot2f(s1.b, w0.b, a10);
        a10 = fdot2f(s1.c, w0.c, a10); a10 = fdot2f(s1.d, w0.d, a10);
        a11 = fdot2f(s1.a, w1.a, a11); a11 = fdot2f(s1.b, w1.b, a11);
        a11 = fdot2f(s1.c, w1.c, a11); a11 = fdot2f(s1.d, w1.d, a11);
    }
    sh[t] = fmaxf(a00, 0.f); sh[t + 256] = fmaxf(a01, 0.f);
    sh[512 + t] = fmaxf(a10, 0.f); sh[512 + t + 256] = fmaxf(a11, 0.f);
}

// ============ k_pre: fp16-packed sweeps, batch-per-thread n1/u split =======
// grid 1178: [0,1024) n1/u (role=bx>>9, bg=(bx&511)>>2, jq=bx&3),
//            [1024,1152) size head, [1152,1178) pW1
__global__ __launch_bounds__(256) void k_pre(
        const float* __restrict__ z, const float* __restrict__ tp,
        const float* __restrict__ b_in,
        const float* __restrict__ b_s1,
        const float* __restrict__ W_s2, const float* __restrict__ b_s2,
        const float* __restrict__ b_n1,
        const float* __restrict__ pe,
        const v2h* __restrict__ W1p, const v2h* __restrict__ Wep,
        const v2h* __restrict__ Wsp, const v2h* __restrict__ Winp,
        float* __restrict__ n1, float* __restrict__ u,
        float* __restrict__ pW1, float* __restrict__ out_sp) {
    int bx = blockIdx.x, t = threadIdx.x;
    __shared__ float smem[2560];

    if (bx < 1024) {
        // ---- role n1 (bx<512) or u: batch-per-thread, 128-col quarter -----
        int role = bx >> 9;
        int idx = bx & 511;
        int bg = idx >> 2, jq = idx & 3;
        int b0 = bg * 2;
        v2h* sin2 = reinterpret_cast<v2h*>(smem);        // 136 v2h
        float* sh  = smem + 136;                          // [2][512]
        v2h* h2    = reinterpret_cast<v2h*>(smem + 1160); // [2][256] v2h
        stage_sin2(sin2, z, tp, b0, t);
        __syncthreads();
        phase1_h(sin2, Winp, b_in, sh, t);
        __syncthreads();
        for (int idx2 = t; idx2 < 512; idx2 += 256) {
            int bi = idx2 >> 8, k2 = idx2 & 255;
            v2h v; v.x = (_Float16)sh[bi * 512 + 2 * k2];
            v.y = (_Float16)sh[bi * 512 + 2 * k2 + 1];
            h2[bi * 256 + k2] = v;
        }
        __syncthreads();
        int bi = t >> 7, jj = t & 127;
        int j = jq * 128 + jj;
        int b = b0 + bi;
        const v2h* Wp = role ? Wep : W1p;
        const v2h* hb = h2 + bi * 256;
        float a0 = 0.f, a0b = 0.f;
#pragma unroll 4
        for (int k8 = 0; k8 < 64; ++k8) {
            h8 ha = *reinterpret_cast<const h8*>(&hb[k8 * 4]);
            h8 w  = *reinterpret_cast<const h8*>(&Wp[(size_t)(k8 * 512 + j) * 4]);
            a0  = fdot2f(ha.a, w.a, a0);  a0  = fdot2f(ha.b, w.b, a0);
            a0b = fdot2f(ha.c, w.c, a0b); a0b = fdot2f(ha.d, w.d, a0b);
        }
        float r0 = a0 + a0b;
        if (role == 0) {
            n1[(size_t)b * HDIM + j] = fmaxf(r0 + b_n1[j], 0.f);
        } else {
            u[(size_t)b * HDIM + j] = r0;
        }
    } else if (bx < 1152) {
        // ---- role size head: 2 batches ------------------------------------
        int b0 = (bx - 1024) * 2;
        v2h* sin2 = reinterpret_cast<v2h*>(smem);
        float* sh  = smem + 136;
        v2h* h2    = reinterpret_cast<v2h*>(smem + 1160);
        float* s1b = smem + 1672;
        float* slg = smem + 2184;
        stage_sin2(sin2, z, tp, b0, t);
        __syncthreads();
        phase1_h(sin2, Winp, b_in, sh, t);
        __syncthreads();
        for (int idx = t; idx < 512; idx += 256) {
            int bi = idx >> 8, k2 = idx & 255;
            v2h v; v.x = (_Float16)sh[bi * 512 + 2 * k2];
            v.y = (_Float16)sh[bi * 512 + 2 * k2 + 1];
            h2[bi * 256 + k2] = v;
        }
        __syncthreads();
        {
            float bv = b_s1[t];
            float a0 = bv, a0b = 0.f, a1 = bv, a1b = 0.f;
            for (int k8 = 0; k8 < 64; ++k8) {
                h8 ha = *reinterpret_cast<const h8*>(&h2[k8 * 4]);
                h8 hb = *reinterpret_cast<const h8*>(&h2[256 + k8 * 4]);
                h8 w  = *reinterpret_cast<const h8*>(&Wsp[(size_t)(k8 * 256 + t) * 4]);
                a0  = fdot2f(ha.a, w.a, a0);  a0  = fdot2f(ha.b, w.b, a0);
                a0b = fdot2f(ha.c, w.c, a0b); a0b = fdot2f(ha.d, w.d, a0b);
                a1  = fdot2f(hb.a, w.a, a1);  a1  = fdot2f(hb.b, w.b, a1);
                a1b = fdot2f(hb.c, w.c, a1b); a1b = fdot2f(hb.d, w.d, a1b);
            }
            s1b[t] = fmaxf(a0 + a0b, 0.f);
            s1b[256 + t] = fmaxf(a1 + a1b, 0.f);
        }
        __syncthreads();
        int b4 = t / NDIM, o = t % NDIM;
        if (t < 2 * NDIM) {
            float a = b_s2[o];
            for (int k = 0; k < HDIM / 2; ++k)
                a += s1b[b4 * 256 + k] * W_s2[(size_t)k * NDIM + o];
            slg[b4 * NDIM + o] = a;
        }
        __syncthreads();
        if (t < 2 * NDIM) {
            float m = slg[b4 * NDIM];
            for (int k = 1; k < NDIM; ++k) m = fmaxf(m, slg[b4 * NDIM + k]);
            float s = 0.f;
            for (int k = 0; k < NDIM; ++k) s += expf(slg[b4 * NDIM + k] - m);
            out_sp[(size_t)(b0 + b4) * NDIM + o] = expf(slg[b4 * NDIM + o] - m) / s;
        }
    } else {
        // ---- role pW1: 0.5 * pe @ W1h, 4 rows x 256-col half --------------
        int g = bx - 1152, rg = g >> 1, jh = g & 1;
        int r[4];
#pragma unroll
        for (int q = 0; q < 4; ++q) { int rr = rg * 4 + q; r[q] = (rr < NDIM) ? rr : NDIM - 1; }
        v2h* pe2 = reinterpret_cast<v2h*>(smem);   // [4][256] v2h
        for (int idx = t; idx < 4 * 256; idx += 256) {
            int row = idx >> 8, k2 = idx & 255;
            v2h v;
            v.x = (_Float16)pe[(size_t)r[row] * HDIM + 2 * k2];
            v.y = (_Float16)pe[(size_t)r[row] * HDIM + 2 * k2 + 1];
            pe2[idx] = v;
        }
        __syncthreads();
        int j = jh * 256 + t;
        float a0 = 0.f, a0b = 0.f, a1 = 0.f, a1b = 0.f;
        float a2 = 0.f, a2b = 0.f, a3 = 0.f, a3b = 0.f;
        for (int k8 = 0; k8 < 64; ++k8) {
            h8 p0 = *reinterpret_cast<const h8*>(&pe2[0 * 256 + k8 * 4]);
            h8 p1 = *reinterpret_cast<const h8*>(&pe2[1 * 256 + k8 * 4]);
            h8 p2 = *reinterpret_cast<const h8*>(&pe2[2 * 256 + k8 * 4]);
            h8 p3 = *reinterpret_cast<const h8*>(&pe2[3 * 256 + k8 * 4]);
            h8 w  = *reinterpret_cast<const h8*>(&Wep[(size_t)(k8 * 512 + j) * 4]);
            a0  = fdot2f(p0.a, w.a, a0);  a0  = fdot2f(p0.b, w.b, a0);
            a0b = fdot2f(p0.c, w.c, a0b); a0b = fdot2f(p0.d, w.d, a0b);
            a1  = fdot2f(p1.a, w.a, a1);  a1  = fdot2f(p1.b, w.b, a1);
            a1b = fdot2f(p1.c, w.c, a1b); a1b = fdot2f(p1.d, w.d, a1b);
            a2  = fdot2f(p2.a, w.a, a2);  a2  = fdot2f(p2.b, w.b, a2);
            a2b = fdot2f(p2.c, w.c, a2b); a2b = fdot2f(p2.d, w.d, a2b);
            a3  = fdot2f(p3.a, w.a, a3);  a3  = fdot2f(p3.b, w.b, a3);
            a3b = fdot2f(p3.c, w.c, a3b); a3b = fdot2f(p3.d, w.d, a3b);
        }
        pW1[(size_t)r[0] * HDIM + j] = 0.5f * (a0 + a0b);
        pW1[(size_t)r[1] * HDIM + j] = 0.5f * (a1 + a1b);
        pW1[(size_t)r[2] * HDIM + j] = 0.5f * (a2 + a2b);
        pW1[(size_t)r[3] * HDIM + j] = 0.5f * (a3 + a3b);
    }
}

// ============ k_nl: fp16-packed W_n2 sweep, 2 batches/block ================
__global__ __launch_bounds__(320) void k_nl(const float* __restrict__ n1,
                                            const v2h* __restrict__ Wn2p,
                                            const float* __restrict__ b_n2,
                                            float* __restrict__ out_nl,
                                            _Float16* __restrict__ nl_h) {
    const int NOUT = NDIM * DDIM;   // 1600
    int t = threadIdx.x;
    int j = blockIdx.y * 320 + t;
    int bg = blockIdx.x;            // 2 batches
    __shared__ v2h h2s[512];        // [2][256]
    for (int idx = t; idx < 512; idx += 320) {
        int bi = idx >> 8, k2 = idx & 255;
        v2h v;
        v.x = (_Float16)n1[(size_t)(bg * 2 + bi) * HDIM + 2 * k2];
        v.y = (_Float16)n1[(size_t)(bg * 2 + bi) * HDIM + 2 * k2 + 1];
        h2s[idx] = v;
    }
    __syncthreads();
    float a0 = 0.f, a0b = 0.f, a1 = 0.f, a1b = 0.f;
    for (int k8 = 0; k8 < 64; ++k8) {
        h8 ha = *reinterpret_cast<const h8*>(&h2s[k8 * 4]);
        h8 hb = *reinterpret_cast<const h8*>(&h2s[256 + k8 * 4]);
        h8 w  = *reinterpret_cast<const h8*>(&Wn2p[((size_t)k8 * 1600 + j) * 4]);
        a0  = fdot2f(ha.a, w.a, a0);  a0  = fdot2f(ha.b, w.b, a0);
        a0b = fdot2f(ha.c, w.c, a0b); a0b = fdot2f(ha.d, w.d, a0b);
        a1  = fdot2f(hb.a, w.a, a1);  a1  = fdot2f(hb.b, w.b, a1);
        a1b = fdot2f(hb.c, w.c, a1b); a1b = fdot2f(hb.d, w.d, a1b);
    }
    float bias = b_n2[j];
    float r0 = bias + a0 + a0b;
    float r1 = bias + a1 + a1b;
    out_nl[(size_t)(bg * 2 + 0) * NOUT + j] = r0;
    out_nl[(size_t)(bg * 2 + 1) * NOUT + j] = r1;
    nl_h[(size_t)(bg * 2 + 0) * NOUT + j] = (_Float16)r0;
    nl_h[(size_t)(bg * 2 + 1) * NOUT + j] = (_Float16)r1;
}

// ============ k_edge: LDS nl broadcast + packed produce weights ============
__global__ __launch_bounds__(256) void k_edge(
        const _Float16* __restrict__ nl_h,  // [256,50,32] fp16
        const float* __restrict__ u,        // [256,512]
        const float* __restrict__ pW1,      // [50,512]
        const v2h* __restrict__ Weeh,       // [2*512][16] packed produce W
        const float* __restrict__ b_e1,     // [512]
        const float* __restrict__ W_e2,     // [512,5]
        _Float16* __restrict__ P) {         // [4][256][1225][5] fp16
    int b  = blockIdx.x;
    int rh = blockIdx.y;
    int t  = threadIdx.x;
    int rbase = rh * ECH;
    constexpr int ech4 = ECH / 4;           // 32

    __shared__ __align__(16) _Float16 Ah[NDIM * ECH];  // 12.8 KB
    __shared__ __align__(16) _Float16 Bh[NDIM * ECH];  // 12.8 KB
    __shared__ v2h W2h[ECH / 2][EOUT];                 // 1.28 KB
    __shared__ __align__(16) v2h nls[NDIM * 16];       // 3.2 KB

    for (int i = t; i < (ECH / 2) * EOUT; i += 256) {
        int p = i / EOUT, o = i - p * EOUT;
        v2h w;
        w.x = (_Float16)W_e2[(size_t)(rbase + 2 * p) * EOUT + o];
        w.y = (_Float16)W_e2[(size_t)(rbase + 2 * p + 1) * EOUT + o];
        W2h[p][o] = w;
    }
    {
        const v2h* g = reinterpret_cast<const v2h*>(nl_h + (size_t)b * (NDIM * DDIM));
        for (int i = t; i < NDIM * 16; i += 256) nls[i] = g[i];
    }
    __syncthreads();

    bool has = (t < 225);
    int pp = 0, qq = 0;
    if (has) {
        int tt = t;
        for (pp = 0; pp < 25; ++pp) {
            int qmin = pp ? ((2 * pp - 2) / 3 + 1) : 0;
            int cnt = 17 - qmin;
            if (tt < cnt) { qq = qmin + tt; break; }
            tt -= cnt;
        }
    }
    int i0 = 2 * pp, i1 = i0 + 1;
    int j0 = 3 * qq, j1 = j0 + 1, j2r = (3 * qq + 2 < NDIM) ? 3 * qq + 2 : NDIM - 1;

    float acc[6][EOUT];
#pragma unroll
    for (int e = 0; e < 6; ++e)
#pragma unroll
        for (int o = 0; o < EOUT; ++o) acc[e][o] = 0.f;

    // ---- produce (packed W via Weeh, nl via LDS broadcast) ----
    {
        int arr = t >> 7, c = t & 127;
        int col = rbase + c;
        const h8* wp = reinterpret_cast<const h8*>(&Weeh[((size_t)arr * 512 + col) * 16]);
        h8 wA = wp[0], wB = wp[1], wC = wp[2], wD = wp[3];
        float cm = 0.5f * (u[(size_t)b * HDIM + col] + b_e1[col]);
        _Float16* dst = arr ? Bh : Ah;
        float pc = pW1[col];
        for (int n = 0; n < NDIM; ++n) {
            float pn = (n < NDIM - 1) ? pW1[(size_t)(n + 1) * HDIM + col] : 0.f;
            const h8* nrp = reinterpret_cast<const h8*>(&nls[n * 16]);
            h8 nA = nrp[0], nB = nrp[1], nC = nrp[2], nD = nrp[3];
            float s0 = 0.f, s1 = 0.f, s2 = 0.f, s3 = 0.f;
            s0 = fdot2f(nA.a, wA.a, s0); s0 = fdot2f(nA.b, wA.b, s0);
            s0 = fdot2f(nA.c, wA.c, s0); s0 = fdot2f(nA.d, wA.d, s0);
            s1 = fdot2f(nB.a, wB.a, s1); s1 = fdot2f(nB.b, wB.b, s1);
            s1 = fdot2f(nB.c, wB.c, s1); s1 = fdot2f(nB.d, wB.d, s1);
            s2 = fdot2f(nC.a, wC.a, s2); s2 = fdot2f(nC.b, wC.b, s2);
            s2 = fdot2f(nC.c, wC.c, s2); s2 = fdot2f(nC.d, wC.d, s2);
            s3 = fdot2f(nD.a, wD.a, s3); s3 = fdot2f(nD.b, wD.b, s3);
            s3 = fdot2f(nD.c, wD.c, s3); s3 = fdot2f(nD.d, wD.d, s3);
            float val = (cm + pc) + ((s0 + s1) + (s2 + s3));
            dst[n * ECH + ((((c >> 2) ^ (n & 7)) << 2) | (c & 3))] = (_Float16)val;
            pc = pn;
        }
    }
    __syncthreads();

    // ---- consume ----
    if (has) {
        int sA = i0 & 7, sB = i1 & 7, s0m = j0 & 7, s1m = j1 & 7, s2m = j2r & 7;
        for (int r4 = 0; r4 < ech4; ++r4) {
            h4 ra0 = *reinterpret_cast<const h4*>(&Ah[i0 * ECH + ((r4 ^ sA) << 2)]);
            h4 ra1 = *reinterpret_cast<const h4*>(&Ah[i1 * ECH + ((r4 ^ sB) << 2)]);
            h4 rb0 = *reinterpret_cast<const h4*>(&Bh[j0 * ECH + ((r4 ^ s0m) << 2)]);
            h4 rb1 = *reinterpret_cast<const h4*>(&Bh[j1 * ECH + ((r4 ^ s1m) << 2)]);
            h4 rb2 = *reinterpret_cast<const h4*>(&Bh[j2r * ECH + ((r4 ^ s2m) << 2)]);
            v2h v0l = relu2(ra0.lo, rb0.lo), v0h = relu2(ra0.hi, rb0.hi);
            v2h v1l = relu2(ra0.lo, rb1.lo), v1h = relu2(ra0.hi, rb1.hi);
            v2h v2l = relu2(ra0.lo, rb2.lo), v2hh = relu2(ra0.hi, rb2.hi);
            v2h v3l = relu2(ra1.lo, rb0.lo), v3h = relu2(ra1.hi, rb0.hi);
            v2h v4l = relu2(ra1.lo, rb1.lo), v4h = relu2(ra1.hi, rb1.hi);
            v2h v5l = relu2(ra1.lo, rb2.lo), v5h = relu2(ra1.hi, rb2.hi);
            int pb = r4 * 2;
#pragma unroll
            for (int o = 0; o < EOUT; ++o) {
                v2h wl = W2h[pb][o], wh = W2h[pb + 1][o];
                acc[0][o] = fdot2f(v0h, wh, fdot2f(v0l, wl, acc[0][o]));
                acc[1][o] = fdot2f(v1h, wh, fdot2f(v1l, wl, acc[1][o]));
                acc[2][o] = fdot2f(v2hh, wh, fdot2f(v2l, wl, acc[2][o]));
                acc[3][o] = fdot2f(v3h, wh, fdot2f(v3l, wl, acc[3][o]));
                acc[4][o] = fdot2f(v4h, wh, fdot2f(v4l, wl, acc[4][o]));
                acc[5][o] = fdot2f(v5h, wh, fdot2f(v5l, wl, acc[5][o]));
            }
        }
    }
    __syncthreads();

    if (has) {
        _Float16* Pb = P + ((size_t)rh * BSZ + b) * NEDGE * EOUT;
        int js[3] = {j0, j1, 3 * qq + 2};
#pragma unroll
        for (int r = 0; r < 2; ++r) {
            int i = i0 + r;
#pragma unroll
            for (int cc = 0; cc < 3; ++cc) {
                int j = js[cc];
                if (i < j && j < NDIM) {
                    int e = i * (NDIM - 1) - (i * (i - 1)) / 2 + (j - i - 1);
#pragma unroll
                    for (int o = 0; o < EOUT; ++o)
                        Pb[(size_t)e * EOUT + o] = (_Float16)acc[r * 3 + cc][o];
                }
            }
        }
    }
}

// ============ k_comb: out_el = sum of 4 fp16 partials + bias ===============
__global__ __launch_bounds__(256) void k_comb(const _Float16* __restrict__ P,
                                              const float* __restrict__ b_e2,
                                              float* __restrict__ out_el,
                                              float* __restrict__ out_idx) {
    int blk = blockIdx.x, t = threadIdx.x;
    const size_t PS = (size_t)BSZ * NEDGE * EOUT;   // 1568000 halves
    if (blk < 766) {
        int tid = blk * 256 + t;       // h8 unit index; 196000 total
        if (tid < 196000) {
            float s[8];
#pragma unroll
            for (int e = 0; e < 8; ++e) s[e] = 0.f;
#pragma unroll
            for (int p = 0; p < NRH; ++p) {
                h8 v = reinterpret_cast<const h8*>(P + (size_t)p * PS)[tid];
                s[0] += (float)v.a.x; s[1] += (float)v.a.y;
                s[2] += (float)v.b.x; s[3] += (float)v.b.y;
                s[4] += (float)v.c.x; s[5] += (float)v.c.y;
                s[6] += (float)v.d.x; s[7] += (float)v.d.y;
            }
            float b5[5];
#pragma unroll
            for (int cc = 0; cc < 5; ++cc) b5[cc] = b_e2[cc];
            size_t base = (size_t)tid * 8;
            int m = (int)(base % 5);
            float4 r0, r1;
#pragma unroll
            for (int e = 0; e < 8; ++e) {
                float val = s[e] + b5[m];
                if (e < 4) (&r0.x)[e] = val; else (&r1.x)[e - 4] = val;
                m = (m + 1 == 5) ? 0 : m + 1;
            }
            reinterpret_cast<float4*>(out_el + base)[0] = r0;
            reinterpret_cast<float4*>(out_el + base)[1] = r1;
        }
    } else {
        int e = (blk - 766) * 256 + t;
        if (e < NEDGE) {
            int i = 0, rem = e;
            while (rem >= (NDIM - 1 - i)) { rem -= (NDIM - 1 - i); ++i; }
            int j = i + 1 + rem;
            out_idx[e * 2] = (float)i;
            out_idx[e * 2 + 1] = (float)j;
        }
    }
}

extern "C" void kernel_launch(void* const* d_in, const int* in_sizes, int n_in,
                              void* d_out, int out_size, void* d_ws, size_t ws_size,
                              hipStream_t stream) {
    const float* z    = (const float*)d_in[0];
    const float* tp   = (const float*)d_in[1];
    const float* W_in = (const float*)d_in[2];
    const float* b_in = (const float*)d_in[3];
    const float* W_s1 = (const float*)d_in[4];
    const float* b_s1 = (const float*)d_in[5];
    const float* W_s2 = (const float*)d_in[6];
    const float* b_s2 = (const float*)d_in[7];
    const float* W_n1 = (const float*)d_in[8];
    const float* b_n1 = (const float*)d_in[9];
    const float* W_n2 = (const float*)d_in[10];
    const float* b_n2 = (const float*)d_in[11];
    const float* W_e1 = (const float*)d_in[12];
    const float* b_e1 = (const float*)d_in[13];
    const float* W_e2 = (const float*)d_in[14];
    const float* b_e2 = (const float*)d_in[15];
    const float* pe   = (const float*)d_in[16];

    float* out     = (float*)d_out;
    float* out_nl  = out;                 // node_logits
    float* out_el  = out + 409600;        // edge_logits
    float* out_sp  = out + 1977600;       // size_probs
    float* out_idx = out + 1990400;       // edge_indices (as float)

    float* ws   = (float*)d_ws;
    float* u    = ws;
    float* pW1  = ws + 131072;
    float* n1   = ws + 156672;
    _Float16* P_h = (_Float16*)(ws + 287744);    // [4][256][1225][5] fp16
    _Float16* nl_h = (_Float16*)(ws + 6559744);  // [256,50,32] fp16
    v2h* W1p  = (v2h*)(ws + 6764544);
    v2h* Wep  = (v2h*)(ws + 6895616);
    v2h* Wsp  = (v2h*)(ws + 7026688);
    v2h* Winp = (v2h*)(ws + 7092224);
    v2h* Wn2p = (v2h*)(ws + 7127040);
    v2h* Weeh = (v2h*)(ws + 7536640);

    k_prep<<<3080, 256, 0, stream>>>(W_n1, W_e1, W_s1, W_in, W_n2,
                                     W1p, Wep, Wsp, Winp, Wn2p, Weeh);
    k_pre<<<1178, 256, 0, stream>>>(z, tp, b_in, b_s1, W_s2, b_s2, b_n1, pe,
                                    W1p, Wep, Wsp, Winp, n1, u, pW1, out_sp);
    k_nl<<<dim3(128, 5), 320, 0, stream>>>(n1, Wn2p, b_n2, out_nl, nl_h);
    k_edge<<<dim3(BSZ, NRH), 256, 0, stream>>>(nl_h, u, pW1, Weeh, b_e1, W_e2, P_h);
    k_comb<<<771, 256, 0, stream>>>(P_h, b_e2, out_el, out_idx);
}

// Round 26
// 91.854 us; speedup vs baseline: 1.0778x; 1.0778x over previous
//
#include <hip/hip_runtime.h>
#include <math.h>

// Problem dims
#define BSZ   256
#define LDIM  128
#define PDIM  3
#define HDIM  512
#define DDIM  32
#define NDIM  50
#define NEDGE 1225   // N*(N-1)/2
#define EOUT  5      // EDIM+1
#define NRH   4      // r-splits: 4 x 128 cols
#define ECH   128    // cols per edge block

// ws layout (floats):
//   u @0 (131072), pW1 @131072 (25600), n1 @156672 (131072),
//   P_h @287744 (3136000 fl), nl_h @6559744 (204800),
//   W1p @6764544 (131072), Wep @6895616 (131072), Wsp @7026688 (65536),
//   Winp @7092224 (34816), Wn2p @7127040 (409600), Weeh @7536640 (16384)

typedef _Float16 v2h __attribute__((ext_vector_type(2)));

__device__ __forceinline__ float fdot2f(v2h a, v2h b, float c) {
    return __builtin_amdgcn_fdot2(a, b, c, false);
}
__device__ __forceinline__ v2h relu2(v2h a, v2h b) {
    v2h s = a + b;
    v2h z = {(_Float16)0.f, (_Float16)0.f};
    return __builtin_elementwise_max(s, z);
}
struct h4 { v2h lo, hi; };
struct h8 { v2h a, b, c, d; };   // 16B

// ============ k_prep: pack weights into fp16 k-pair layouts ================
__global__ __launch_bounds__(256) void k_prep(
        const float* __restrict__ W_n1, const float* __restrict__ W_e1,
        const float* __restrict__ W_s1, const float* __restrict__ W_in,
        const float* __restrict__ W_n2,
        v2h* __restrict__ W1p, v2h* __restrict__ Wep,
        v2h* __restrict__ Wsp, v2h* __restrict__ Winp,
        v2h* __restrict__ Wn2p, v2h* __restrict__ Weeh) {
    int f = blockIdx.x * 256 + threadIdx.x;
    if (f < 131072) {
        int q = f & 3, t1 = f >> 2, j = t1 & 511, k8 = t1 >> 9;
        int k2 = k8 * 4 + q;
        v2h w;
        w.x = (_Float16)W_n1[(size_t)(2 * k2) * HDIM + j];
        w.y = (_Float16)W_n1[(size_t)(2 * k2 + 1) * HDIM + j];
        W1p[f] = w;
    } else if (f < 262144) {
        int g = f - 131072;
        int q = g & 3, t1 = g >> 2, j = t1 & 511, k8 = t1 >> 9;
        int k2 = k8 * 4 + q;
        v2h w;
        w.x = (_Float16)W_e1[(size_t)(2 * k2) * HDIM + j];
        w.y = (_Float16)W_e1[(size_t)(2 * k2 + 1) * HDIM + j];
        Wep[g] = w;
    } else if (f < 327680) {
        int g = f - 262144;
        int q = g & 3, t1 = g >> 2, j = t1 & 255, k8 = t1 >> 8;
        int k2 = k8 * 4 + q;
        v2h w;
        w.x = (_Float16)W_s1[(size_t)(2 * k2) * (HDIM / 2) + j];
        w.y = (_Float16)W_s1[(size_t)(2 * k2 + 1) * (HDIM / 2) + j];
        Wsp[g] = w;
    } else if (f < 362496) {
        int g = f - 327680;
        int q = g & 3, t1 = g >> 2, j = t1 & 511, k8 = t1 >> 9;
        int k2 = k8 * 4 + q;     // 0..67
        int r0 = 2 * k2, r1 = 2 * k2 + 1;
        v2h w;
        w.x = (r0 < LDIM + PDIM) ? (_Float16)W_in[(size_t)r0 * HDIM + j] : (_Float16)0.f;
        w.y = (r1 < LDIM + PDIM) ? (_Float16)W_in[(size_t)r1 * HDIM + j] : (_Float16)0.f;
        Winp[g] = w;
    } else if (f < 772096) {
        int g = f - 362496;
        int q = g & 3, t1 = g >> 2;      // t1 < 102400
        int j = t1 % 1600, k8 = t1 / 1600;   // k8 < 64
        int k2 = k8 * 4 + q;             // < 256
        v2h w;
        w.x = (_Float16)W_n2[(size_t)(2 * k2) * 1600 + j];
        w.y = (_Float16)W_n2[(size_t)(2 * k2 + 1) * 1600 + j];
        Wn2p[g] = w;
    } else if (f < 772096 + 16384) {
        int g = f - 772096;              // [arr][col][k2]
        int k2 = g & 15, col = (g >> 4) & 511, arr = g >> 13;
        v2h w;
        w.x = (_Float16)W_e1[(size_t)(HDIM + arr * DDIM + 2 * k2) * HDIM + col];
        w.y = (_Float16)W_e1[(size_t)(HDIM + arr * DDIM + 2 * k2 + 1) * HDIM + col];
        Weeh[g] = w;
    }
}

// helper: stage packed inputs [2][68] v2h from z/tp
__device__ __forceinline__ void stage_sin2(v2h* sin2, const float* z, const float* tp,
                                           int b0, int t) {
    if (t < 136) {
        int bi = (t >= 68) ? 1 : 0;
        int k2 = t - (bi ? 68 : 0);
        int k0 = 2 * k2, k1 = 2 * k2 + 1;
        float v0 = (k0 < LDIM) ? z[(size_t)(b0 + bi) * LDIM + k0]
                 : (k0 < LDIM + PDIM) ? tp[(size_t)(b0 + bi) * PDIM + (k0 - LDIM)] : 0.f;
        float v1 = (k1 < LDIM) ? z[(size_t)(b0 + bi) * LDIM + k1]
                 : (k1 < LDIM + PDIM) ? tp[(size_t)(b0 + bi) * PDIM + (k1 - LDIM)] : 0.f;
        v2h v; v.x = (_Float16)v0; v.y = (_Float16)v1;
        sin2[bi * 68 + k2] = v;
    }
}

// helper: phase1 h for 2 batches via packed W_in; writes sh[2][512] fp32
__device__ __forceinline__ void phase1_h(const v2h* sin2, const v2h* Winp,
                                         const float* b_in, float* sh, int t) {
    float bin0 = b_in[t], bin1 = b_in[t + 256];
    float a00 = bin0, a01 = bin1, a10 = bin0, a11 = bin1;
    for (int k8 = 0; k8 < 17; ++k8) {
        h8 s0 = *reinterpret_cast<const h8*>(&sin2[k8 * 4]);
        h8 s1 = *reinterpret_cast<const h8*>(&sin2[68 + k8 * 4]);
        h8 w0 = *reinterpret_cast<const h8*>(&Winp[(size_t)(k8 * 512 + t) * 4]);
        h8 w1 = *reinterpret_cast<const h8*>(&Winp[(size_t)(k8 * 512 + t + 256) * 4]);
        a00 = fdot2f(s0.a, w0.a, a00); a00 = fdot2f(s0.b, w0.b, a00);
        a00 = fdot2f(s0.c, w0.c, a00); a00 = fdot2f(s0.d, w0.d, a00);
        a01 = fdot2f(s0.a, w1.a, a01); a01 = fdot2f(s0.b, w1.b, a01);
        a01 = fdot2f(s0.c, w1.c, a01); a01 = fdot2f(s0.d, w1.d, a01);
        a10 = fdot2f(s1.a, w0.a, a10); a10 = fdot2f(s1.b, w0.b, a10);
        a10 = fdot2f(s1.c, w0.c, a10); a10 = fdot2f(s1.d, w0.d, a10);
        a11 = fdot2f(s1.a, w1.a, a11); a11 = fdot2f(s1.b, w1.b, a11);
        a11 = fdot2f(s1.c, w1.c, a11); a11 = fdot2f(s1.d, w1.d, a11);
    }
    sh[t] = fmaxf(a00, 0.f); sh[t + 256] = fmaxf(a01, 0.f);
    sh[512 + t] = fmaxf(a10, 0.f); sh[512 + t + 256] = fmaxf(a11, 0.f);
}

// ============ k_pre: fp16-packed sweeps (round-21/24 champion) =============
__global__ __launch_bounds__(256) void k_pre(
        const float* __restrict__ z, const float* __restrict__ tp,
        const float* __restrict__ b_in,
        const float* __restrict__ b_s1,
        const float* __restrict__ W_s2, const float* __restrict__ b_s2,
        const float* __restrict__ b_n1,
        const float* __restrict__ pe,
        const v2h* __restrict__ W1p, const v2h* __restrict__ Wep,
        const v2h* __restrict__ Wsp, const v2h* __restrict__ Winp,
        float* __restrict__ n1, float* __restrict__ u,
        float* __restrict__ pW1, float* __restrict__ out_sp) {
    int bx = blockIdx.x, t = threadIdx.x;
    __shared__ float smem[2560];

    if (bx < 512) {
        int role = bx >> 8;
        int idx2 = bx & 255;
        int bg = idx2 >> 1, jh = idx2 & 1;
        int b0 = bg * 2;
        v2h* sin2 = reinterpret_cast<v2h*>(smem);        // 136 v2h
        float* sh  = smem + 136;                          // [2][512]
        v2h* h2    = reinterpret_cast<v2h*>(smem + 1160); // [2][256] v2h
        stage_sin2(sin2, z, tp, b0, t);
        __syncthreads();
        phase1_h(sin2, Winp, b_in, sh, t);
        __syncthreads();
        for (int idx = t; idx < 512; idx += 256) {
            int bi = idx >> 8, k2 = idx & 255;
            v2h v; v.x = (_Float16)sh[bi * 512 + 2 * k2];
            v.y = (_Float16)sh[bi * 512 + 2 * k2 + 1];
            h2[bi * 256 + k2] = v;
        }
        __syncthreads();
        int j = jh * 256 + t;
        const v2h* Wp = role ? Wep : W1p;
        float a0 = 0.f, a0b = 0.f, a1 = 0.f, a1b = 0.f;
        for (int k8 = 0; k8 < 64; ++k8) {
            h8 ha = *reinterpret_cast<const h8*>(&h2[k8 * 4]);
            h8 hb = *reinterpret_cast<const h8*>(&h2[256 + k8 * 4]);
            h8 w  = *reinterpret_cast<const h8*>(&Wp[(size_t)(k8 * 512 + j) * 4]);
            a0  = fdot2f(ha.a, w.a, a0);  a0  = fdot2f(ha.b, w.b, a0);
            a0b = fdot2f(ha.c, w.c, a0b); a0b = fdot2f(ha.d, w.d, a0b);
            a1  = fdot2f(hb.a, w.a, a1);  a1  = fdot2f(hb.b, w.b, a1);
            a1b = fdot2f(hb.c, w.c, a1b); a1b = fdot2f(hb.d, w.d, a1b);
        }
        float r0 = a0 + a0b, r1 = a1 + a1b;
        if (role == 0) {
            float bb = b_n1[j];
            n1[(size_t)(b0 + 0) * HDIM + j] = fmaxf(r0 + bb, 0.f);
            n1[(size_t)(b0 + 1) * HDIM + j] = fmaxf(r1 + bb, 0.f);
        } else {
            u[(size_t)(b0 + 0) * HDIM + j] = r0;
            u[(size_t)(b0 + 1) * HDIM + j] = r1;
        }
    } else if (bx < 640) {
        int b0 = (bx - 512) * 2;
        v2h* sin2 = reinterpret_cast<v2h*>(smem);
        float* sh  = smem + 136;
        v2h* h2    = reinterpret_cast<v2h*>(smem + 1160);
        float* s1b = smem + 1672;
        float* slg = smem + 2184;
        stage_sin2(sin2, z, tp, b0, t);
        __syncthreads();
        phase1_h(sin2, Winp, b_in, sh, t);
        __syncthreads();
        for (int idx = t; idx < 512; idx += 256) {
            int bi = idx >> 8, k2 = idx & 255;
            v2h v; v.x = (_Float16)sh[bi * 512 + 2 * k2];
            v.y = (_Float16)sh[bi * 512 + 2 * k2 + 1];
            h2[bi * 256 + k2] = v;
        }
        __syncthreads();
        {
            float bv = b_s1[t];
            float a0 = bv, a0b = 0.f, a1 = bv, a1b = 0.f;
            for (int k8 = 0; k8 < 64; ++k8) {
                h8 ha = *reinterpret_cast<const h8*>(&h2[k8 * 4]);
                h8 hb = *reinterpret_cast<const h8*>(&h2[256 + k8 * 4]);
                h8 w  = *reinterpret_cast<const h8*>(&Wsp[(size_t)(k8 * 256 + t) * 4]);
                a0  = fdot2f(ha.a, w.a, a0);  a0  = fdot2f(ha.b, w.b, a0);
                a0b = fdot2f(ha.c, w.c, a0b); a0b = fdot2f(ha.d, w.d, a0b);
                a1  = fdot2f(hb.a, w.a, a1);  a1  = fdot2f(hb.b, w.b, a1);
                a1b = fdot2f(hb.c, w.c, a1b); a1b = fdot2f(hb.d, w.d, a1b);
            }
            s1b[t] = fmaxf(a0 + a0b, 0.f);
            s1b[256 + t] = fmaxf(a1 + a1b, 0.f);
        }
        __syncthreads();
        int b4 = t / NDIM, o = t % NDIM;
        if (t < 2 * NDIM) {
            float a = b_s2[o];
            for (int k = 0; k < HDIM / 2; ++k)
                a += s1b[b4 * 256 + k] * W_s2[(size_t)k * NDIM + o];
            slg[b4 * NDIM + o] = a;
        }
        __syncthreads();
        if (t < 2 * NDIM) {
            float m = slg[b4 * NDIM];
            for (int k = 1; k < NDIM; ++k) m = fmaxf(m, slg[b4 * NDIM + k]);
            float s = 0.f;
            for (int k = 0; k < NDIM; ++k) s += expf(slg[b4 * NDIM + k] - m);
            out_sp[(size_t)(b0 + b4) * NDIM + o] = expf(slg[b4 * NDIM + o] - m) / s;
        }
    } else {
        int g = bx - 640, rg = g >> 1, jh = g & 1;
        int r[4];
#pragma unroll
        for (int q = 0; q < 4; ++q) { int rr = rg * 4 + q; r[q] = (rr < NDIM) ? rr : NDIM - 1; }
        v2h* pe2 = reinterpret_cast<v2h*>(smem);   // [4][256] v2h
        for (int idx = t; idx < 4 * 256; idx += 256) {
            int row = idx >> 8, k2 = idx & 255;
            v2h v;
            v.x = (_Float16)pe[(size_t)r[row] * HDIM + 2 * k2];
            v.y = (_Float16)pe[(size_t)r[row] * HDIM + 2 * k2 + 1];
            pe2[idx] = v;
        }
        __syncthreads();
        int j = jh * 256 + t;
        float a0 = 0.f, a0b = 0.f, a1 = 0.f, a1b = 0.f;
        float a2 = 0.f, a2b = 0.f, a3 = 0.f, a3b = 0.f;
        for (int k8 = 0; k8 < 64; ++k8) {
            h8 p0 = *reinterpret_cast<const h8*>(&pe2[0 * 256 + k8 * 4]);
            h8 p1 = *reinterpret_cast<const h8*>(&pe2[1 * 256 + k8 * 4]);
            h8 p2 = *reinterpret_cast<const h8*>(&pe2[2 * 256 + k8 * 4]);
            h8 p3 = *reinterpret_cast<const h8*>(&pe2[3 * 256 + k8 * 4]);
            h8 w  = *reinterpret_cast<const h8*>(&Wep[(size_t)(k8 * 512 + j) * 4]);
            a0  = fdot2f(p0.a, w.a, a0);  a0  = fdot2f(p0.b, w.b, a0);
            a0b = fdot2f(p0.c, w.c, a0b); a0b = fdot2f(p0.d, w.d, a0b);
            a1  = fdot2f(p1.a, w.a, a1);  a1  = fdot2f(p1.b, w.b, a1);
            a1b = fdot2f(p1.c, w.c, a1b); a1b = fdot2f(p1.d, w.d, a1b);
            a2  = fdot2f(p2.a, w.a, a2);  a2  = fdot2f(p2.b, w.b, a2);
            a2b = fdot2f(p2.c, w.c, a2b); a2b = fdot2f(p2.d, w.d, a2b);
            a3  = fdot2f(p3.a, w.a, a3);  a3  = fdot2f(p3.b, w.b, a3);
            a3b = fdot2f(p3.c, w.c, a3b); a3b = fdot2f(p3.d, w.d, a3b);
        }
        pW1[(size_t)r[0] * HDIM + j] = 0.5f * (a0 + a0b);
        pW1[(size_t)r[1] * HDIM + j] = 0.5f * (a1 + a1b);
        pW1[(size_t)r[2] * HDIM + j] = 0.5f * (a2 + a2b);
        pW1[(size_t)r[3] * HDIM + j] = 0.5f * (a3 + a3b);
    }
}

// ============ k_nl: fp16-packed W_n2 sweep, 2 batches/block ================
__global__ __launch_bounds__(320) void k_nl(const float* __restrict__ n1,
                                            const v2h* __restrict__ Wn2p,
                                            const float* __restrict__ b_n2,
                                            float* __restrict__ out_nl,
                                            _Float16* __restrict__ nl_h) {
    const int NOUT = NDIM * DDIM;   // 1600
    int t = threadIdx.x;
    int j = blockIdx.y * 320 + t;
    int bg = blockIdx.x;            // 2 batches
    __shared__ v2h h2s[512];        // [2][256]
    for (int idx = t; idx < 512; idx += 320) {
        int bi = idx >> 8, k2 = idx & 255;
        v2h v;
        v.x = (_Float16)n1[(size_t)(bg * 2 + bi) * HDIM + 2 * k2];
        v.y = (_Float16)n1[(size_t)(bg * 2 + bi) * HDIM + 2 * k2 + 1];
        h2s[idx] = v;
    }
    __syncthreads();
    float a0 = 0.f, a0b = 0.f, a1 = 0.f, a1b = 0.f;
    for (int k8 = 0; k8 < 64; ++k8) {
        h8 ha = *reinterpret_cast<const h8*>(&h2s[k8 * 4]);
        h8 hb = *reinterpret_cast<const h8*>(&h2s[256 + k8 * 4]);
        h8 w  = *reinterpret_cast<const h8*>(&Wn2p[((size_t)k8 * 1600 + j) * 4]);
        a0  = fdot2f(ha.a, w.a, a0);  a0  = fdot2f(ha.b, w.b, a0);
        a0b = fdot2f(ha.c, w.c, a0b); a0b = fdot2f(ha.d, w.d, a0b);
        a1  = fdot2f(hb.a, w.a, a1);  a1  = fdot2f(hb.b, w.b, a1);
        a1b = fdot2f(hb.c, w.c, a1b); a1b = fdot2f(hb.d, w.d, a1b);
    }
    float bias = b_n2[j];
    float r0 = bias + a0 + a0b;
    float r1 = bias + a1 + a1b;
    out_nl[(size_t)(bg * 2 + 0) * NOUT + j] = r0;
    out_nl[(size_t)(bg * 2 + 1) * NOUT + j] = r1;
    nl_h[(size_t)(bg * 2 + 0) * NOUT + j] = (_Float16)r0;
    nl_h[(size_t)(bg * 2 + 1) * NOUT + j] = (_Float16)r1;
}

// ============ k_edge: LDS nl broadcast + packed produce weights ============
__global__ __launch_bounds__(256) void k_edge(
        const _Float16* __restrict__ nl_h,  // [256,50,32] fp16
        const float* __restrict__ u,        // [256,512]
        const float* __restrict__ pW1,      // [50,512]
        const v2h* __restrict__ Weeh,       // [2*512][16] packed produce W
        const float* __restrict__ b_e1,     // [512]
        const float* __restrict__ W_e2,     // [512,5]
        _Float16* __restrict__ P) {         // [4][256][1225][5] fp16
    int b  = blockIdx.x;
    int rh = blockIdx.y;
    int t  = threadIdx.x;
    int rbase = rh * ECH;
    constexpr int ech4 = ECH / 4;           // 32

    __shared__ __align__(16) _Float16 Ah[NDIM * ECH];  // 12.8 KB
    __shared__ __align__(16) _Float16 Bh[NDIM * ECH];  // 12.8 KB
    __shared__ v2h W2h[ECH / 2][EOUT];                 // 1.28 KB
    __shared__ __align__(16) v2h nls[NDIM * 16];       // 3.2 KB

    for (int i = t; i < (ECH / 2) * EOUT; i += 256) {
        int p = i / EOUT, o = i - p * EOUT;
        v2h w;
        w.x = (_Float16)W_e2[(size_t)(rbase + 2 * p) * EOUT + o];
        w.y = (_Float16)W_e2[(size_t)(rbase + 2 * p + 1) * EOUT + o];
        W2h[p][o] = w;
    }
    {
        const v2h* g = reinterpret_cast<const v2h*>(nl_h + (size_t)b * (NDIM * DDIM));
        for (int i = t; i < NDIM * 16; i += 256) nls[i] = g[i];
    }
    __syncthreads();

    bool has = (t < 225);
    int pp = 0, qq = 0;
    if (has) {
        int tt = t;
        for (pp = 0; pp < 25; ++pp) {
            int qmin = pp ? ((2 * pp - 2) / 3 + 1) : 0;
            int cnt = 17 - qmin;
            if (tt < cnt) { qq = qmin + tt; break; }
            tt -= cnt;
        }
    }
    int i0 = 2 * pp, i1 = i0 + 1;
    int j0 = 3 * qq, j1 = j0 + 1, j2r = (3 * qq + 2 < NDIM) ? 3 * qq + 2 : NDIM - 1;

    float acc[6][EOUT];
#pragma unroll
    for (int e = 0; e < 6; ++e)
#pragma unroll
        for (int o = 0; o < EOUT; ++o) acc[e][o] = 0.f;

    // ---- produce (packed W via Weeh, nl via LDS broadcast) ----
    {
        int arr = t >> 7, c = t & 127;
        int col = rbase + c;
        const h8* wp = reinterpret_cast<const h8*>(&Weeh[((size_t)arr * 512 + col) * 16]);
        h8 wA = wp[0], wB = wp[1], wC = wp[2], wD = wp[3];
        float cm = 0.5f * (u[(size_t)b * HDIM + col] + b_e1[col]);
        _Float16* dst = arr ? Bh : Ah;
        float pc = pW1[col];
        for (int n = 0; n < NDIM; ++n) {
            float pn = (n < NDIM - 1) ? pW1[(size_t)(n + 1) * HDIM + col] : 0.f;
            const h8* nrp = reinterpret_cast<const h8*>(&nls[n * 16]);
            h8 nA = nrp[0], nB = nrp[1], nC = nrp[2], nD = nrp[3];
            float s0 = 0.f, s1 = 0.f, s2 = 0.f, s3 = 0.f;
            s0 = fdot2f(nA.a, wA.a, s0); s0 = fdot2f(nA.b, wA.b, s0);
            s0 = fdot2f(nA.c, wA.c, s0); s0 = fdot2f(nA.d, wA.d, s0);
            s1 = fdot2f(nB.a, wB.a, s1); s1 = fdot2f(nB.b, wB.b, s1);
            s1 = fdot2f(nB.c, wB.c, s1); s1 = fdot2f(nB.d, wB.d, s1);
            s2 = fdot2f(nC.a, wC.a, s2); s2 = fdot2f(nC.b, wC.b, s2);
            s2 = fdot2f(nC.c, wC.c, s2); s2 = fdot2f(nC.d, wC.d, s2);
            s3 = fdot2f(nD.a, wD.a, s3); s3 = fdot2f(nD.b, wD.b, s3);
            s3 = fdot2f(nD.c, wD.c, s3); s3 = fdot2f(nD.d, wD.d, s3);
            float val = (cm + pc) + ((s0 + s1) + (s2 + s3));
            dst[n * ECH + ((((c >> 2) ^ (n & 7)) << 2) | (c & 3))] = (_Float16)val;
            pc = pn;
        }
    }
    __syncthreads();

    // ---- consume ----
    if (has) {
        int sA = i0 & 7, sB = i1 & 7, s0m = j0 & 7, s1m = j1 & 7, s2m = j2r & 7;
        for (int r4 = 0; r4 < ech4; ++r4) {
            h4 ra0 = *reinterpret_cast<const h4*>(&Ah[i0 * ECH + ((r4 ^ sA) << 2)]);
            h4 ra1 = *reinterpret_cast<const h4*>(&Ah[i1 * ECH + ((r4 ^ sB) << 2)]);
            h4 rb0 = *reinterpret_cast<const h4*>(&Bh[j0 * ECH + ((r4 ^ s0m) << 2)]);
            h4 rb1 = *reinterpret_cast<const h4*>(&Bh[j1 * ECH + ((r4 ^ s1m) << 2)]);
            h4 rb2 = *reinterpret_cast<const h4*>(&Bh[j2r * ECH + ((r4 ^ s2m) << 2)]);
            v2h v0l = relu2(ra0.lo, rb0.lo), v0h = relu2(ra0.hi, rb0.hi);
            v2h v1l = relu2(ra0.lo, rb1.lo), v1h = relu2(ra0.hi, rb1.hi);
            v2h v2l = relu2(ra0.lo, rb2.lo), v2hh = relu2(ra0.hi, rb2.hi);
            v2h v3l = relu2(ra1.lo, rb0.lo), v3h = relu2(ra1.hi, rb0.hi);
            v2h v4l = relu2(ra1.lo, rb1.lo), v4h = relu2(ra1.hi, rb1.hi);
            v2h v5l = relu2(ra1.lo, rb2.lo), v5h = relu2(ra1.hi, rb2.hi);
            int pb = r4 * 2;
#pragma unroll
            for (int o = 0; o < EOUT; ++o) {
                v2h wl = W2h[pb][o], wh = W2h[pb + 1][o];
                acc[0][o] = fdot2f(v0h, wh, fdot2f(v0l, wl, acc[0][o]));
                acc[1][o] = fdot2f(v1h, wh, fdot2f(v1l, wl, acc[1][o]));
                acc[2][o] = fdot2f(v2hh, wh, fdot2f(v2l, wl, acc[2][o]));
                acc[3][o] = fdot2f(v3h, wh, fdot2f(v3l, wl, acc[3][o]));
                acc[4][o] = fdot2f(v4h, wh, fdot2f(v4l, wl, acc[4][o]));
                acc[5][o] = fdot2f(v5h, wh, fdot2f(v5l, wl, acc[5][o]));
            }
        }
    }
    __syncthreads();

    if (has) {
        _Float16* Pb = P + ((size_t)rh * BSZ + b) * NEDGE * EOUT;
        int js[3] = {j0, j1, 3 * qq + 2};
#pragma unroll
        for (int r = 0; r < 2; ++r) {
            int i = i0 + r;
#pragma unroll
            for (int cc = 0; cc < 3; ++cc) {
                int j = js[cc];
                if (i < j && j < NDIM) {
                    int e = i * (NDIM - 1) - (i * (i - 1)) / 2 + (j - i - 1);
#pragma unroll
                    for (int o = 0; o < EOUT; ++o)
                        Pb[(size_t)e * EOUT + o] = (_Float16)acc[r * 3 + cc][o];
                }
            }
        }
    }
}

// ============ k_comb: out_el = sum of 4 fp16 partials + bias ===============
__global__ __launch_bounds__(256) void k_comb(const _Float16* __restrict__ P,
                                              const float* __restrict__ b_e2,
                                              float* __restrict__ out_el,
                                              float* __restrict__ out_idx) {
    int blk = blockIdx.x, t = threadIdx.x;
    const size_t PS = (size_t)BSZ * NEDGE * EOUT;   // 1568000 halves
    if (blk < 766) {
        int tid = blk * 256 + t;       // h8 unit index; 196000 total
        if (tid < 196000) {
            float s[8];
#pragma unroll
            for (int e = 0; e < 8; ++e) s[e] = 0.f;
#pragma unroll
            for (int p = 0; p < NRH; ++p) {
                h8 v = reinterpret_cast<const h8*>(P + (size_t)p * PS)[tid];
                s[0] += (float)v.a.x; s[1] += (float)v.a.y;
                s[2] += (float)v.b.x; s[3] += (float)v.b.y;
                s[4] += (float)v.c.x; s[5] += (float)v.c.y;
                s[6] += (float)v.d.x; s[7] += (float)v.d.y;
            }
            float b5[5];
#pragma unroll
            for (int cc = 0; cc < 5; ++cc) b5[cc] = b_e2[cc];
            size_t base = (size_t)tid * 8;
            int m = (int)(base % 5);
            float4 r0, r1;
#pragma unroll
            for (int e = 0; e < 8; ++e) {
                float val = s[e] + b5[m];
                if (e < 4) (&r0.x)[e] = val; else (&r1.x)[e - 4] = val;
                m = (m + 1 == 5) ? 0 : m + 1;
            }
            reinterpret_cast<float4*>(out_el + base)[0] = r0;
            reinterpret_cast<float4*>(out_el + base)[1] = r1;
        }
    } else {
        int e = (blk - 766) * 256 + t;
        if (e < NEDGE) {
            int i = 0, rem = e;
            while (rem >= (NDIM - 1 - i)) { rem -= (NDIM - 1 - i); ++i; }
            int j = i + 1 + rem;
            out_idx[e * 2] = (float)i;
            out_idx[e * 2 + 1] = (float)j;
        }
    }
}

extern "C" void kernel_launch(void* const* d_in, const int* in_sizes, int n_in,
                              void* d_out, int out_size, void* d_ws, size_t ws_size,
                              hipStream_t stream) {
    const float* z    = (const float*)d_in[0];
    const float* tp   = (const float*)d_in[1];
    const float* W_in = (const float*)d_in[2];
    const float* b_in = (const float*)d_in[3];
    const float* W_s1 = (const float*)d_in[4];
    const float* b_s1 = (const float*)d_in[5];
    const float* W_s2 = (const float*)d_in[6];
    const float* b_s2 = (const float*)d_in[7];
    const float* W_n1 = (const float*)d_in[8];
    const float* b_n1 = (const float*)d_in[9];
    const float* W_n2 = (const float*)d_in[10];
    const float* b_n2 = (const float*)d_in[11];
    const float* W_e1 = (const float*)d_in[12];
    const float* b_e1 = (const float*)d_in[13];
    const float* W_e2 = (const float*)d_in[14];
    const float* b_e2 = (const float*)d_in[15];
    const float* pe   = (const float*)d_in[16];

    float* out     = (float*)d_out;
    float* out_nl  = out;                 // node_logits
    float* out_el  = out + 409600;        // edge_logits
    float* out_sp  = out + 1977600;       // size_probs
    float* out_idx = out + 1990400;       // edge_indices (as float)

    float* ws   = (float*)d_ws;
    float* u    = ws;
    float* pW1  = ws + 131072;
    float* n1   = ws + 156672;
    _Float16* P_h = (_Float16*)(ws + 287744);    // [4][256][1225][5] fp16
    _Float16* nl_h = (_Float16*)(ws + 6559744);  // [256,50,32] fp16
    v2h* W1p  = (v2h*)(ws + 6764544);
    v2h* Wep  = (v2h*)(ws + 6895616);
    v2h* Wsp  = (v2h*)(ws + 7026688);
    v2h* Winp = (v2h*)(ws + 7092224);
    v2h* Wn2p = (v2h*)(ws + 7127040);
    v2h* Weeh = (v2h*)(ws + 7536640);

    k_prep<<<3080, 256, 0, stream>>>(W_n1, W_e1, W_s1, W_in, W_n2,
                                     W1p, Wep, Wsp, Winp, Wn2p, Weeh);
    k_pre<<<666, 256, 0, stream>>>(z, tp, b_in, b_s1, W_s2, b_s2, b_n1, pe,
                                   W1p, Wep, Wsp, Winp, n1, u, pW1, out_sp);
    k_nl<<<dim3(128, 5), 320, 0, stream>>>(n1, Wn2p, b_n2, out_nl, nl_h);
    k_edge<<<dim3(BSZ, NRH), 256, 0, stream>>>(nl_h, u, pW1, Weeh, b_e1, W_e2, P_h);
    k_comb<<<771, 256, 0, stream>>>(P_h, b_e2, out_el, out_idx);
}